// Round 4
// baseline (159.763 us; speedup 1.0000x reference)
//
#include <hip/hip_runtime.h>

// SimplePitchEstimator on MI355X (gfx950).
// ac = irfft(rfft(x,512)^2) == linear self-convolution c[n] = sum_m y[m]*y[n-m],
// y = x - mean(x) (support 318 < 512, no wrap). Direct fp32 conv.
//
// Round-4 design (vs round 3):
//  * FULLY STATIC conv schedule: macro-rounds of 20 m-steps; w[34]+x loads use
//    compile-time LDS offsets (ds imm / ds_read2-mergeable), no sliding-window
//    movs, no runtime address math. Entire tile unrolled -> compiler software-
//    pipelines ds_reads across macro boundaries (partial lgkmcnt waits) so the
//    per-round read->waitcnt->FMA lockstep stall of rounds 1-3 disappears.
//  * Dirty tail (n-m < 0 terms) resolved at COMPILE TIME: invalid FMAs pruned,
//    no selects, no zero-padding waste. Per-acc summation stays m-ascending ->
//    bitwise-identical to round 3 (absmax 0).
//  * Kept: LDS = 160x64x4 = 40960 B exactly (4 blocks/CU, all 1024 blocks
//    co-resident), balanced lag pairs (54/55/55/54 rounds), mu folded at
//    LDS-write, aux reductions multiplexed into X rows.

#define SR_F    16000.0f
#define HOPSZ   256
#define FPB     64
#define TFRAMES 4096
#define SAMPLES 1048576

// Tile: lags N0..N0+14, m = 0..4R-1 (R = ceil((N0+15)/4)).
template<int N0, int R>
__device__ __forceinline__ void conv_tile(const float* __restrict__ X, int f,
                                          float& best, int& bl) {
    constexpr int J = 15;
    constexpr int FULL   = R / 5;                      // macro-iters of 5 rounds
    constexpr int CLEANQ = (N0 - 19) / 20 + 1;         // macros with w-rows >= 0
    constexpr int CLEAN  = (CLEANQ < FULL) ? CLEANQ : FULL;
    constexpr int M0     = CLEAN * 20;                 // first m of static tail
    constexpr int WHI    = N0 + 14 - M0;               // highest w row in tail

    float acc[J];
    #pragma unroll
    for (int j = 0; j < J; ++j) acc[j] = 0.f;

    // ---- clean macros: m = 20*mu .. 20*mu+19, all w rows >= 0 ----
    #pragma unroll
    for (int mu = 0; mu < CLEAN; ++mu) {
        const int w0 = N0 - 19 - 20 * mu;              // lowest w row (>= 0)
        float w[34];
        #pragma unroll
        for (int t = 0; t < 34; ++t)
            w[t] = X[(w0 + t) * FPB + f];              // static offsets
        #pragma unroll
        for (int k = 0; k < 5; ++k) {
            const float x0 = X[(20*mu + 4*k + 0) * FPB + f];
            const float x1 = X[(20*mu + 4*k + 1) * FPB + f];
            const float x2 = X[(20*mu + 4*k + 2) * FPB + f];
            const float x3 = X[(20*mu + 4*k + 3) * FPB + f];
            #pragma unroll
            for (int j = 0; j < J; ++j) {              // m ascending per acc
                acc[j] = fmaf(x0, w[j + 19 - 4*k], acc[j]);
                acc[j] = fmaf(x1, w[j + 18 - 4*k], acc[j]);
                acc[j] = fmaf(x2, w[j + 17 - 4*k], acc[j]);
                acc[j] = fmaf(x3, w[j + 16 - 4*k], acc[j]);
            }
        }
    }

    // ---- static tail: m = M0 .. 4R-1; negative rows pruned at compile time ----
    {
        float wd[WHI + 1];
        #pragma unroll
        for (int t = 0; t <= WHI; ++t)
            wd[t] = X[t * FPB + f];
        #pragma unroll
        for (int m = M0; m < 4 * R; ++m) {
            if (m <= N0 + 14) {                        // compile-time prune
                const float xv = X[m * FPB + f];
                #pragma unroll
                for (int j = 0; j < J; ++j) {
                    const int row = N0 + j - m;        // compile-time constant
                    if (row >= 0)
                        acc[j] = fmaf(xv, wd[row], acc[j]);
                }
            }
        }
    }

    // ---- local argmax: first-max (ascending lag order) ----
    #pragma unroll
    for (int j = 0; j < J; ++j)
        if (acc[j] > best) { best = acc[j]; bl = N0 + j; }
}

__global__ __launch_bounds__(256, 4)
void pitch_kernel(const float* __restrict__ audio, float* __restrict__ out) {
    __shared__ float X[160 * FPB];     // 40960 B exactly -> 4 blocks/CU

    const int tid = threadIdx.x;
    const int s   = tid >> 6;          // wave id
    const int f   = tid & 63;          // frame within block
    const int blk = blockIdx.x;
    const int b   = blk >> 6;          // batch row
    const int t0  = (blk & 63) << 6;   // first frame of block

    // ---- Phase A: load 40 samples of frame f (chunk s), partial sum ----
    const float* g = audio + (size_t)b * SAMPLES + (size_t)(t0 + f) * HOPSZ + s * 40;
    float v[40];
    float ps = 0.f;
    #pragma unroll
    for (int j = 0; j < 10; ++j) {
        float4 q = reinterpret_cast<const float4*>(g)[j];   // 16B-aligned
        v[4*j+0] = q.x; v[4*j+1] = q.y; v[4*j+2] = q.z; v[4*j+3] = q.w;
        ps += q.x + q.y + q.z + q.w;
    }

    // ---- Phase B: block mean via aux rows 0-3 ----
    X[s * 64 + f] = ps;
    __syncthreads();
    const float mu = (X[f] + X[64 + f] + X[128 + f] + X[192 + f]) * (1.0f / 160.0f);
    float pm = 0.f;
    #pragma unroll
    for (int q = 0; q < 40; ++q) pm = fmaxf(pm, fabsf(v[q] - mu));
    __syncthreads();                       // sum-reads done

    // ---- Phase C: silent-check partial max via aux rows 0-3 ----
    X[s * 64 + f] = pm;
    __syncthreads();
    float mx = 0.f;
    if (s == 0)
        mx = fmaxf(fmaxf(X[f], X[64 + f]), fmaxf(X[128 + f], X[192 + f]));
    __syncthreads();                       // pm-reads done

    // ---- Phase D: write centered frames, transposed, lane-stride-1 ----
    #pragma unroll
    for (int q = 0; q < 40; ++q)
        X[(s * 40 + q) * FPB + f] = v[q] - mu;
    __syncthreads();

    // ---- Phase E: paired balanced tiles (low + high lags) ----
    float best = -3.4e38f; int bl = 0;
    if      (s == 0) { conv_tile< 40, 14>(X, f, best, bl);   // 14 rounds
                       conv_tile<145, 40>(X, f, best, bl); } // +40 = 54
    else if (s == 1) { conv_tile< 55, 18>(X, f, best, bl);
                       conv_tile<130, 37>(X, f, best, bl); } // 55
    else if (s == 2) { conv_tile< 70, 22>(X, f, best, bl);
                       conv_tile<115, 33>(X, f, best, bl); } // 55
    else             { conv_tile< 85, 25>(X, f, best, bl);
                       conv_tile<100, 29>(X, f, best, bl); } // 54
    __syncthreads();                       // conv done: X now dead

    // ---- Phase F: cross-wave argmax via aux rows 0-7 ----
    X[s * 64 + f] = best;
    reinterpret_cast<int*>(X)[256 + s * 64 + f] = bl;
    __syncthreads();

    if (s == 0) {
        float bv = X[f];
        int   L  = reinterpret_cast<int*>(X)[256 + f];
        #pragma unroll
        for (int c = 1; c < 4; ++c) {
            const float vv = X[c * 64 + f];
            const int   lv = reinterpret_cast<int*>(X)[256 + c * 64 + f];
            if (vv > bv || (vv == bv && lv < L)) { bv = vv; L = lv; }
        }
        const float pitch = SR_F / (float)L;
        out[(size_t)b * TFRAMES + t0 + f] = (mx < 1e-8f) ? 0.0f : pitch;
    }
}

extern "C" void kernel_launch(void* const* d_in, const int* in_sizes, int n_in,
                              void* d_out, int out_size, void* d_ws, size_t ws_size,
                              hipStream_t stream) {
    const float* audio = (const float*)d_in[0];
    float* out = (float*)d_out;
    pitch_kernel<<<dim3(1024), dim3(256), 0, stream>>>(audio, out);
}

// Round 6
// 112.280 us; speedup vs baseline: 1.4229x; 1.4229x over previous
//
#include <hip/hip_runtime.h>

// SimplePitchEstimator on MI355X (gfx950).
// ac = irfft(rfft(x,512)^2) == linear self-convolution c[n] = sum y[i]y[n-i],
// y = x - mean(x). Round-6: symmetric half-sum + quad-row b128 LDS layout,
// circular window fixed to WQ=8 for all tiles (round 5's WQ=6 assert failed
// for N0 % 4 == 2, and odd WQ would break xb parity across trips).
//
//  * c[n] = 2*sum_{i<ceil(n/2)} y[i]*y[n-i] + (n even ? y[n/2]^2 : 0)
//    -> halves MACs (12060 -> ~6050/frame), removes all negative rows.
//  * LDS layout X4[quad][frame]: float4 of rows 4q..4q+3 at column f.
//    All conv reads are lane-contiguous ds_read_b128 (conflict-free):
//    2 reads per 60-FMA round.
//  * w-window = 8-quad circular register file, slot = quad % 8 (compile-time).
//    Window spans W4 in {5,6} quads + 1 prefetch = <=7 consecutive quads ->
//    always distinct mod 8. WQ even -> xb[k&1] parity consistent across trips.
//    Runtime trips of exactly 8 rounds; remainder+ragged rounds statically
//    unrolled with compile-time validity pruning. Bounded unroll -> no spill.
//  * Kept: LDS 40960 B exactly (4 blocks/CU, 1024 blocks co-resident),
//    balanced tile pairs (27/27/28/28 rounds), mu folded at LDS write,
//    aux reductions multiplexed into X rows.

#define SR_F    16000.0f
#define HOPSZ   256
#define TFRAMES 4096
#define SAMPLES 1048576

template<int N0>
__device__ __forceinline__ void conv_tile(const float4* __restrict__ X4, int f,
                                          float& best, int& bl) {
    constexpr int J  = 15;
    constexpr int B0 = ((N0 - 3) / 4) * 4;            // aligned window base row
    constexpr int Q0 = B0 / 4;                        // base quad
    constexpr int W4 = (N0 + J - 1) / 4 - Q0 + 1;     // quads covering window
    constexpr int WQ = 8;                             // circular slots (even!)
    constexpr int RC = (N0 + 1) / 8;                  // rounds valid for all j,d
    constexpr int IEND = (N0 + J) / 2;                // i < IEND overall
    constexpr int RT = (IEND + 3) / 4;                // total rounds
    constexpr int T  = RC / WQ;                       // runtime trips
    constexpr int R0 = T * WQ;                        // first static round
    static_assert(W4 <= WQ - 1, "window + prefetch must fit in slots");
    static_assert(RC <= RT - 1, "runtime prefetch must stay in range");
    static_assert(Q0 - RT + 1 >= 0, "refill quad negative");
    // centers must lie in final resident window [Q0-RT+1, Q0-RT+WQ] (quads):
    static_assert(4 * (Q0 - RT + 1) <= N0 / 2, "center below window");
    static_assert((N0 + J - 1) / 2 < 4 * (Q0 - RT + 1) + 4 * WQ, "center above");

    float acc[J];
    #pragma unroll
    for (int j = 0; j < J; ++j) acc[j] = 0.f;

    float4 wq[WQ];
    float4 xb[2];
    const float4* col = X4 + f;

    // prologue: window quads Q0..Q0+W4-1 (slot = quad % WQ), x quad 0
    #pragma unroll
    for (int i = 0; i < W4; ++i)
        wq[(Q0 + i) % WQ] = col[(Q0 + i) * 64];
    xb[0] = col[0];

#define WQ_GET(slot_, comp_) \
    ((comp_) == 0 ? wq[slot_].x : (comp_) == 1 ? wq[slot_].y : \
     (comp_) == 2 ? wq[slot_].z : wq[slot_].w)

    // one round with r == K (mod WQ); MASKR: compile-time validity (2i < n)
#define PITCH_ROUND(K, MASKR)                                             \
    {                                                                     \
        const float4 xc = xb[(K) & 1];                                    \
        _Pragma("unroll")                                                 \
        for (int d = 0; d < 4; ++d) {                                     \
            const float xv = d == 0 ? xc.x : d == 1 ? xc.y                \
                           : d == 2 ? xc.z : xc.w;                        \
            _Pragma("unroll")                                             \
            for (int j = 0; j < J; ++j) {                                 \
                if (2 * (4 * (MASKR) + d) < N0 + j) {                     \
                    const int q    = N0 + j - d;                          \
                    const int slot = ((q / 4 - (K)) % WQ + WQ) % WQ;      \
                    const int comp = q & 3;                               \
                    acc[j] = fmaf(xv, WQ_GET(slot, comp), acc[j]);        \
                }                                                         \
            }                                                             \
        }                                                                 \
    }

    // ---- runtime trips: rounds r = t*WQ + k, all (j,d) valid (r < RC) ----
    const float4* xp = col + 64;                    // x quad r+1 at trip base
    const float4* wp = col + (Q0 - WQ) * 64;        // refill quads, trip base
    #pragma unroll 1
    for (int t = 0; t < T; ++t) {
        #pragma unroll
        for (int k = 0; k < WQ; ++k) {
            // prefetch round r+1 (r+1 <= T*WQ <= RC <= RT-1: always valid)
            xb[(k + 1) & 1] = xp[k * 64];
            wq[((Q0 - 1 - k) % WQ + WQ) % WQ] = wp[(WQ - 1 - k) * 64];
            PITCH_ROUND(k, 0)                        // mask folds to true
        }
        xp += WQ * 64;
        wp -= WQ * 64;
    }

    // ---- static rounds r = R0..RT-1 (remainder + ragged) ----
    #pragma unroll
    for (int u = 0; u < RT - R0; ++u) {
        const int r = R0 + u;                        // constant after unroll
        if (r + 1 < RT) {                            // compile-time guard
            xb[(r + 1) & 1] = col[(r + 1) * 64];
            wq[((Q0 - 1 - r) % WQ + WQ) % WQ] = col[(Q0 - 1 - r) * 64];
        }
        PITCH_ROUND(r % WQ, r)
    }

    // ---- finalize: x2, center term for even lags, local argmax ----
    #pragma unroll
    for (int j = 0; j < J; ++j) {
        float v2 = acc[j] + acc[j];
        if ((N0 + j) % 2 == 0) {
            const int row  = (N0 + j) / 2;
            const int slot = (row / 4) % WQ;
            const int comp = row & 3;
            const float c  = WQ_GET(slot, comp);
            v2 = fmaf(c, c, v2);
        }
        if (v2 > best) { best = v2; bl = N0 + j; }   // strict >: first max
    }
#undef PITCH_ROUND
#undef WQ_GET
}

__global__ __launch_bounds__(256, 4)
void pitch_kernel(const float* __restrict__ audio, float* __restrict__ out) {
    __shared__ float4 X4[40 * 64];                   // 40960 B exactly
    float* Xa = reinterpret_cast<float*>(X4);

    const int tid = threadIdx.x;
    const int s   = tid >> 6;          // wave id
    const int f   = tid & 63;          // frame within block
    const int blk = blockIdx.x;
    const int b   = blk >> 6;          // batch row
    const int t0  = (blk & 63) << 6;   // first frame of block

    // ---- Phase A: load 40 samples of frame f (chunk s), partial sum ----
    const float* g = audio + (size_t)b * SAMPLES + (size_t)(t0 + f) * HOPSZ + s * 40;
    float v[40];
    float ps = 0.f;
    #pragma unroll
    for (int j = 0; j < 10; ++j) {
        float4 q = reinterpret_cast<const float4*>(g)[j];   // 16B-aligned
        v[4*j+0] = q.x; v[4*j+1] = q.y; v[4*j+2] = q.z; v[4*j+3] = q.w;
        ps += q.x + q.y + q.z + q.w;
    }

    // ---- Phase B: block mean via aux ----
    Xa[s * 64 + f] = ps;
    __syncthreads();
    const float mu = (Xa[f] + Xa[64 + f] + Xa[128 + f] + Xa[192 + f]) * (1.0f / 160.0f);
    float pm = 0.f;
    #pragma unroll
    for (int q = 0; q < 40; ++q) pm = fmaxf(pm, fabsf(v[q] - mu));
    __syncthreads();                       // sum-reads done

    // ---- Phase C: silent-check partial max via aux ----
    Xa[s * 64 + f] = pm;
    __syncthreads();
    float mx = 0.f;
    if (s == 0)
        mx = fmaxf(fmaxf(Xa[f], Xa[64 + f]), fmaxf(Xa[128 + f], Xa[192 + f]));
    __syncthreads();                       // pm-reads done

    // ---- Phase D: write centered frames as row-quads (b128, contiguous) ----
    #pragma unroll
    for (int k = 0; k < 10; ++k)
        X4[(10 * s + k) * 64 + f] =
            make_float4(v[4*k+0] - mu, v[4*k+1] - mu, v[4*k+2] - mu, v[4*k+3] - mu);
    __syncthreads();

    // ---- Phase E: paired balanced tiles (rounds: 27/27/28/28) ----
    float best = -3.4e38f; int bl = 0;
    if      (s == 0) { conv_tile< 40>(X4, f, best, bl);
                       conv_tile<145>(X4, f, best, bl); }
    else if (s == 1) { conv_tile< 55>(X4, f, best, bl);
                       conv_tile<130>(X4, f, best, bl); }
    else if (s == 2) { conv_tile< 70>(X4, f, best, bl);
                       conv_tile<115>(X4, f, best, bl); }
    else             { conv_tile< 85>(X4, f, best, bl);
                       conv_tile<100>(X4, f, best, bl); }
    __syncthreads();                       // conv done: X now dead

    // ---- Phase F: cross-wave argmax via aux ----
    Xa[s * 64 + f] = best;
    reinterpret_cast<int*>(Xa)[256 + s * 64 + f] = bl;
    __syncthreads();

    if (s == 0) {
        float bv = Xa[f];
        int   L  = reinterpret_cast<int*>(Xa)[256 + f];
        #pragma unroll
        for (int c = 1; c < 4; ++c) {
            const float vv = Xa[c * 64 + f];
            const int   lv = reinterpret_cast<int*>(Xa)[256 + c * 64 + f];
            if (vv > bv || (vv == bv && lv < L)) { bv = vv; L = lv; }
        }
        const float pitch = SR_F / (float)L;
        out[(size_t)b * TFRAMES + t0 + f] = (mx < 1e-8f) ? 0.0f : pitch;
    }
}

extern "C" void kernel_launch(void* const* d_in, const int* in_sizes, int n_in,
                              void* d_out, int out_size, void* d_ws, size_t ws_size,
                              hipStream_t stream) {
    const float* audio = (const float*)d_in[0];
    float* out = (float*)d_out;
    pitch_kernel<<<dim3(1024), dim3(256), 0, stream>>>(audio, out);
}

// Round 7
// 106.063 us; speedup vs baseline: 1.5063x; 1.0586x over previous
//
#include <hip/hip_runtime.h>

// SimplePitchEstimator on MI355X (gfx950).
// ac = irfft(rfft(x,512)^2) == linear self-convolution c[n] = sum y[i]y[n-i],
// y = x - mean(x). Round-7: round-6 algorithm (validated absmax=0) + the two
// register-pressure levers:
//
//  * amdgpu_waves_per_eu(4,4): LDS (40960 B) already caps occupancy at
//    4 blocks/CU = 4 waves/EU, but the compiler's heuristic was targeting
//    8 waves/EU -> 64-VGPR cap -> spills (WRITE_SIZE 33-135 MB in rounds
//    2/4/6; VGPR_Count pinned at 64 every round). max=4 unlocks 128 VGPRs.
//  * __builtin_amdgcn_sched_barrier(0) after every conv round: stops the
//    scheduler from hoisting ALL loads of an unrolled multi-round body
//    (the +64-reg spill amplifier) while keeping the intended 1-round
//    software pipeline: prefetch (2 x b128) issues before 60 FMAs, is
//    consumed next round.
//
// Algorithm (validated in round 6):
//  * c[n] = 2*sum_{i<ceil(n/2)} y[i]*y[n-i] + (n even ? y[n/2]^2 : 0)
//    -> ~6050 MACs/frame (half of direct), no negative rows.
//  * LDS X4[quad][frame]: float4 of rows 4q..4q+3 at column f; all conv
//    reads lane-contiguous ds_read_b128, 2 reads per 60-FMA round.
//  * w-window = 8-quad circular register file, slot = quad % 8, all
//    compile-time; runtime trips of 8 rounds; static remainder pruned.
//  * LDS = 40960 B exactly (4 blocks/CU, all 1024 blocks co-resident),
//    balanced tile pairs (27/27/28/28 rounds), mu folded at LDS write,
//    aux reductions multiplexed into X rows.

#define SR_F    16000.0f
#define HOPSZ   256
#define TFRAMES 4096
#define SAMPLES 1048576

template<int N0>
__device__ __forceinline__ void conv_tile(const float4* __restrict__ X4, int f,
                                          float& best, int& bl) {
    constexpr int J  = 15;
    constexpr int B0 = ((N0 - 3) / 4) * 4;            // aligned window base row
    constexpr int Q0 = B0 / 4;                        // base quad
    constexpr int W4 = (N0 + J - 1) / 4 - Q0 + 1;     // quads covering window
    constexpr int WQ = 8;                             // circular slots (even)
    constexpr int RC = (N0 + 1) / 8;                  // rounds valid for all j,d
    constexpr int IEND = (N0 + J) / 2;                // i < IEND overall
    constexpr int RT = (IEND + 3) / 4;                // total rounds
    constexpr int T  = RC / WQ;                       // runtime trips
    constexpr int R0 = T * WQ;                        // first static round
    static_assert(W4 <= WQ - 1, "window + prefetch must fit in slots");
    static_assert(RC <= RT - 1, "runtime prefetch must stay in range");
    static_assert(Q0 - RT + 1 >= 0, "refill quad negative");
    static_assert(4 * (Q0 - RT + 1) <= N0 / 2, "center below window");
    static_assert((N0 + J - 1) / 2 < 4 * (Q0 - RT + 1) + 4 * WQ, "center above");

    float acc[J];
    #pragma unroll
    for (int j = 0; j < J; ++j) acc[j] = 0.f;

    float4 wq[WQ];
    float4 xb[2];
    const float4* col = X4 + f;

    // prologue: window quads Q0..Q0+W4-1 (slot = quad % WQ), x quad 0
    #pragma unroll
    for (int i = 0; i < W4; ++i)
        wq[(Q0 + i) % WQ] = col[(Q0 + i) * 64];
    xb[0] = col[0];

#define WQ_GET(slot_, comp_) \
    ((comp_) == 0 ? wq[slot_].x : (comp_) == 1 ? wq[slot_].y : \
     (comp_) == 2 ? wq[slot_].z : wq[slot_].w)

    // one round with r == K (mod WQ); MASKR: compile-time validity (2i < n)
#define PITCH_ROUND(K, MASKR)                                             \
    {                                                                     \
        const float4 xc = xb[(K) & 1];                                    \
        _Pragma("unroll")                                                 \
        for (int d = 0; d < 4; ++d) {                                     \
            const float xv = d == 0 ? xc.x : d == 1 ? xc.y                \
                           : d == 2 ? xc.z : xc.w;                        \
            _Pragma("unroll")                                             \
            for (int j = 0; j < J; ++j) {                                 \
                if (2 * (4 * (MASKR) + d) < N0 + j) {                     \
                    const int q    = N0 + j - d;                          \
                    const int slot = ((q / 4 - (K)) % WQ + WQ) % WQ;      \
                    const int comp = q & 3;                               \
                    acc[j] = fmaf(xv, WQ_GET(slot, comp), acc[j]);        \
                }                                                         \
            }                                                             \
        }                                                                 \
    }

    // ---- runtime trips: rounds r = t*WQ + k, all (j,d) valid (r < RC) ----
    const float4* xp = col + 64;                    // x quad r+1 at trip base
    const float4* wp = col + (Q0 - WQ) * 64;        // refill quads, trip base
    #pragma unroll 1
    for (int t = 0; t < T; ++t) {
        #pragma unroll
        for (int k = 0; k < WQ; ++k) {
            // prefetch round r+1 (r+1 <= T*WQ <= RC <= RT-1: always valid)
            xb[(k + 1) & 1] = xp[k * 64];
            wq[((Q0 - 1 - k) % WQ + WQ) % WQ] = wp[(WQ - 1 - k) * 64];
            PITCH_ROUND(k, 0)                        // mask folds to true
            __builtin_amdgcn_sched_barrier(0);       // cap live loads: 1 round
        }
        xp += WQ * 64;
        wp -= WQ * 64;
    }

    // ---- static rounds r = R0..RT-1 (remainder + ragged) ----
    #pragma unroll
    for (int u = 0; u < RT - R0; ++u) {
        const int r = R0 + u;                        // constant after unroll
        if (r + 1 < RT) {                            // compile-time guard
            xb[(r + 1) & 1] = col[(r + 1) * 64];
            wq[((Q0 - 1 - r) % WQ + WQ) % WQ] = col[(Q0 - 1 - r) * 64];
        }
        PITCH_ROUND(r % WQ, r)
        __builtin_amdgcn_sched_barrier(0);
    }

    // ---- finalize: x2, center term for even lags, local argmax ----
    #pragma unroll
    for (int j = 0; j < J; ++j) {
        float v2 = acc[j] + acc[j];
        if ((N0 + j) % 2 == 0) {
            const int row  = (N0 + j) / 2;
            const int slot = (row / 4) % WQ;
            const int comp = row & 3;
            const float c  = WQ_GET(slot, comp);
            v2 = fmaf(c, c, v2);
        }
        if (v2 > best) { best = v2; bl = N0 + j; }   // strict >: first max
    }
#undef PITCH_ROUND
#undef WQ_GET
}

__global__ __attribute__((amdgpu_flat_work_group_size(256, 256),
                          amdgpu_waves_per_eu(4, 4)))
void pitch_kernel(const float* __restrict__ audio, float* __restrict__ out) {
    __shared__ float4 X4[40 * 64];                   // 40960 B exactly
    float* Xa = reinterpret_cast<float*>(X4);

    const int tid = threadIdx.x;
    const int s   = tid >> 6;          // wave id
    const int f   = tid & 63;          // frame within block
    const int blk = blockIdx.x;
    const int b   = blk >> 6;          // batch row
    const int t0  = (blk & 63) << 6;   // first frame of block

    // ---- Phase A: load 40 samples of frame f (chunk s), partial sum ----
    const float* g = audio + (size_t)b * SAMPLES + (size_t)(t0 + f) * HOPSZ + s * 40;
    float v[40];
    float ps = 0.f;
    #pragma unroll
    for (int j = 0; j < 10; ++j) {
        float4 q = reinterpret_cast<const float4*>(g)[j];   // 16B-aligned
        v[4*j+0] = q.x; v[4*j+1] = q.y; v[4*j+2] = q.z; v[4*j+3] = q.w;
        ps += q.x + q.y + q.z + q.w;
    }

    // ---- Phase B: block mean via aux ----
    Xa[s * 64 + f] = ps;
    __syncthreads();
    const float mu = (Xa[f] + Xa[64 + f] + Xa[128 + f] + Xa[192 + f]) * (1.0f / 160.0f);
    float pm = 0.f;
    #pragma unroll
    for (int q = 0; q < 40; ++q) pm = fmaxf(pm, fabsf(v[q] - mu));
    __syncthreads();                       // sum-reads done

    // ---- Phase C: silent-check partial max via aux ----
    Xa[s * 64 + f] = pm;
    __syncthreads();
    float mx = 0.f;
    if (s == 0)
        mx = fmaxf(fmaxf(Xa[f], Xa[64 + f]), fmaxf(Xa[128 + f], Xa[192 + f]));
    __syncthreads();                       // pm-reads done

    // ---- Phase D: write centered frames as row-quads (b128, contiguous) ----
    #pragma unroll
    for (int k = 0; k < 10; ++k)
        X4[(10 * s + k) * 64 + f] =
            make_float4(v[4*k+0] - mu, v[4*k+1] - mu, v[4*k+2] - mu, v[4*k+3] - mu);
    __syncthreads();

    // ---- Phase E: paired balanced tiles (rounds: 27/27/28/28) ----
    float best = -3.4e38f; int bl = 0;
    if      (s == 0) { conv_tile< 40>(X4, f, best, bl);
                       conv_tile<145>(X4, f, best, bl); }
    else if (s == 1) { conv_tile< 55>(X4, f, best, bl);
                       conv_tile<130>(X4, f, best, bl); }
    else if (s == 2) { conv_tile< 70>(X4, f, best, bl);
                       conv_tile<115>(X4, f, best, bl); }
    else             { conv_tile< 85>(X4, f, best, bl);
                       conv_tile<100>(X4, f, best, bl); }
    __syncthreads();                       // conv done: X now dead

    // ---- Phase F: cross-wave argmax via aux ----
    Xa[s * 64 + f] = best;
    reinterpret_cast<int*>(Xa)[256 + s * 64 + f] = bl;
    __syncthreads();

    if (s == 0) {
        float bv = Xa[f];
        int   L  = reinterpret_cast<int*>(Xa)[256 + f];
        #pragma unroll
        for (int c = 1; c < 4; ++c) {
            const float vv = Xa[c * 64 + f];
            const int   lv = reinterpret_cast<int*>(Xa)[256 + c * 64 + f];
            if (vv > bv || (vv == bv && lv < L)) { bv = vv; L = lv; }
        }
        const float pitch = SR_F / (float)L;
        out[(size_t)b * TFRAMES + t0 + f] = (mx < 1e-8f) ? 0.0f : pitch;
    }
}

extern "C" void kernel_launch(void* const* d_in, const int* in_sizes, int n_in,
                              void* d_out, int out_size, void* d_ws, size_t ws_size,
                              hipStream_t stream) {
    const float* audio = (const float*)d_in[0];
    float* out = (float*)d_out;
    pitch_kernel<<<dim3(1024), dim3(256), 0, stream>>>(audio, out);
}

// Round 8
// 101.725 us; speedup vs baseline: 1.5705x; 1.0426x over previous
//
#include <hip/hip_runtime.h>

// SimplePitchEstimator on MI355X (gfx950).
// ac = irfft(rfft(x,512)^2) == linear self-convolution c[n] = sum y[i]y[n-i],
// y = x - mean(x). Round-8: half-sum algorithm (validated r6/r7) rebuilt on a
// PROVABLY-FOLDABLE register structure.
//
// Diagnosis of r6/r7: the circular-window arrays (wq[slot%8], xb[k&1]) were
// demoted to scratch (failed constant-folding of modular slot indices inside
// an unrolled-in-runtime-loop body): r6 VALUBusy 0.2%, WRITE_SIZE 33 MB.
// Round 3's literal-affine w[j+3] pattern provably stays in registers.
//
// This round:
//  * c[n] = 2*sum_{2i<n} y[i]*y[n-i] + (n even ? y[n/2]^2 : 0)  (half MACs)
//  * plain float w[24] sliding window, shift-by-4 w/ explicit movs; all FMA
//    indices are w[KOFF + j - d] with KOFF a template constant (foldable).
//  * x-quad and refill-quad as NAMED float4 vars, ds_read_b128, explicit
//    1-round prefetch (loaded at body top, consumed next round).
//    LDS: 2 b128 / 60-FMA round = 384 cy/CU-round vs 704 VALU -> VALU-bound
//    (r3's 8x b32/round was LDS-pipe-co-limited: 742 cy/CU-round).
//  * runtime clean loop (#pragma unroll 1) + <=3-round static masked tail
//    (affine masks 8r+2d < N0+j only; loads never pruned, never OOB).
//  * Kept: LDS 160x64x4 = 40960 B exactly (4 blocks/CU, 1024 co-resident),
//    balanced tile pairs (27/27/28/28 rounds), mu folded at LDS write,
//    aux reductions multiplexed into X, waves_per_eu(4,4) for VGPR headroom.

#define SR_F    16000.0f
#define HOPSZ   256
#define TFRAMES 4096
#define SAMPLES 1048576

// Tile: lags N0..N0+14 via half-sum. col4 = X4 + f (quad q at col4[q*64]),
// colf = (float*)X4 + 4*f (row R at colf[(R/4)*256 + (R&3)]).
template<int N0>
__device__ __forceinline__ void conv_tile(const float4* __restrict__ col4,
                                          const float* __restrict__ colf,
                                          float& best, int& bl) {
    constexpr int J    = 15;
    constexpr int B0   = ((N0 - 3) / 4) * 4;   // window base row (aligned)
    constexpr int Q0   = B0 / 4;               // base quad
    constexpr int KOFF = N0 - B0;              // FMA index offset, 3..6
    constexpr int IC   = (N0 + 14 + 1) / 2;    // i-count for max lag
    constexpr int RT   = (IC + 3) / 4;         // total rounds
    constexpr int RC   = (N0 - 6 + 7) / 8;     // first ragged round
    static_assert(RC >= 1 && RC <= RT - 1, "clean/ragged split");
    static_assert(Q0 - (RT - 1) >= 0, "refill quad in range");
    static_assert(KOFF + J - 1 <= 20, "window index bound");

    float acc[J];
    #pragma unroll
    for (int j = 0; j < J; ++j) acc[j] = 0.f;

    // ---- window init: rows B0..B0+23 (clip quads > 39; w[21..23] unused) ----
    float w[24];
    #pragma unroll
    for (int i = 0; i < 6; ++i) {
        float4 q = (Q0 + i <= 39) ? col4[(Q0 + i) * 64]
                                  : make_float4(0.f, 0.f, 0.f, 0.f);
        w[4*i+0] = q.x; w[4*i+1] = q.y; w[4*i+2] = q.z; w[4*i+3] = q.w;
    }
    float4 xc = col4[0];                       // x quad for round 0

#define TILE_FMA_CLEAN                                                   \
    _Pragma("unroll")                                                    \
    for (int d = 0; d < 4; ++d) {                                        \
        const float xv = d == 0 ? xc.x : d == 1 ? xc.y                   \
                       : d == 2 ? xc.z : xc.w;                           \
        _Pragma("unroll")                                                \
        for (int j = 0; j < J; ++j)                                      \
            acc[j] = fmaf(xv, w[KOFF + j - d], acc[j]);                  \
    }

#define TILE_SHIFT_INSERT                                                \
    _Pragma("unroll")                                                    \
    for (int t = 23; t >= 4; --t) w[t] = w[t - 4];                       \
    w[0] = wn.x; w[1] = wn.y; w[2] = wn.z; w[3] = wn.w;

    // ---- clean rounds r = 0..RC-1 (all terms valid; prefetch r+1) ----
    #pragma unroll 1
    for (int r = 0; r < RC; ++r) {
        float4 xn = col4[(r + 1) * 64];            // x quad, round r+1
        float4 wn = col4[(Q0 - (r + 1)) * 64];     // refill quad, round r+1
        TILE_FMA_CLEAN
        TILE_SHIFT_INSERT
        xc = xn;
    }

    // ---- static tail r = RC..RT-1: masked FMAs (8r+2d < N0+j), same flow ----
    #pragma unroll
    for (int u = 0; u < RT - RC; ++u) {
        const int r = RC + u;                      // constant after unroll
        #pragma unroll
        for (int d = 0; d < 4; ++d) {
            const float xv = d == 0 ? xc.x : d == 1 ? xc.y
                           : d == 2 ? xc.z : xc.w;
            #pragma unroll
            for (int j = 0; j < J; ++j)
                if (8 * r + 2 * d < N0 + j)        // compile-time prune
                    acc[j] = fmaf(xv, w[KOFF + j - d], acc[j]);
        }
        if (r + 1 < RT) {                          // compile-time guard
            float4 wn = col4[(Q0 - (r + 1)) * 64];
            TILE_SHIFT_INSERT
            xc = col4[(r + 1) * 64];
        }
    }
#undef TILE_FMA_CLEAN
#undef TILE_SHIFT_INSERT

    // ---- finalize: x2 + center term (read from LDS), local argmax ----
    #pragma unroll
    for (int j = 0; j < J; ++j) {
        float v2 = acc[j] + acc[j];
        if ((N0 + j) % 2 == 0) {
            constexpr int dummy = 0; (void)dummy;
            const int R = (N0 + j) / 2;            // constant after unroll
            const float c = colf[(R / 4) * 256 + (R & 3)];
            v2 = fmaf(c, c, v2);
        }
        if (v2 > best) { best = v2; bl = N0 + j; } // strict >: first max
    }
}

__global__ __attribute__((amdgpu_flat_work_group_size(256, 256),
                          amdgpu_waves_per_eu(4, 4)))
void pitch_kernel(const float* __restrict__ audio, float* __restrict__ out) {
    __shared__ float4 X4[40 * 64];                 // 40960 B exactly
    float* Xa = reinterpret_cast<float*>(X4);

    const int tid = threadIdx.x;
    const int s   = tid >> 6;          // wave id
    const int f   = tid & 63;          // frame within block
    const int blk = blockIdx.x;
    const int b   = blk >> 6;          // batch row
    const int t0  = (blk & 63) << 6;   // first frame of block

    // ---- Phase A: load 40 samples of frame f (chunk s), partial sum ----
    const float* g = audio + (size_t)b * SAMPLES + (size_t)(t0 + f) * HOPSZ + s * 40;
    float v[40];
    float ps = 0.f;
    #pragma unroll
    for (int j = 0; j < 10; ++j) {
        float4 q = reinterpret_cast<const float4*>(g)[j];   // 16B-aligned
        v[4*j+0] = q.x; v[4*j+1] = q.y; v[4*j+2] = q.z; v[4*j+3] = q.w;
        ps += q.x + q.y + q.z + q.w;
    }

    // ---- Phase B: block mean via aux ----
    Xa[s * 64 + f] = ps;
    __syncthreads();
    const float mu = (Xa[f] + Xa[64 + f] + Xa[128 + f] + Xa[192 + f]) * (1.0f / 160.0f);
    float pm = 0.f;
    #pragma unroll
    for (int q = 0; q < 40; ++q) pm = fmaxf(pm, fabsf(v[q] - mu));
    __syncthreads();                       // sum-reads done

    // ---- Phase C: silent-check partial max via aux ----
    Xa[s * 64 + f] = pm;
    __syncthreads();
    float mx = 0.f;
    if (s == 0)
        mx = fmaxf(fmaxf(Xa[f], Xa[64 + f]), fmaxf(Xa[128 + f], Xa[192 + f]));
    __syncthreads();                       // pm-reads done

    // ---- Phase D: write centered frames as row-quads (b128, contiguous) ----
    #pragma unroll
    for (int k = 0; k < 10; ++k)
        X4[(10 * s + k) * 64 + f] =
            make_float4(v[4*k+0] - mu, v[4*k+1] - mu, v[4*k+2] - mu, v[4*k+3] - mu);
    __syncthreads();

    // ---- Phase E: paired balanced tiles (rounds 27/27/28/28) ----
    const float4* col4 = X4 + f;
    const float*  colf = Xa + 4 * f;
    float best = -3.4e38f; int bl = 0;
    if      (s == 0) { conv_tile< 40>(col4, colf, best, bl);
                       conv_tile<145>(col4, colf, best, bl); }
    else if (s == 1) { conv_tile< 55>(col4, colf, best, bl);
                       conv_tile<130>(col4, colf, best, bl); }
    else if (s == 2) { conv_tile< 70>(col4, colf, best, bl);
                       conv_tile<115>(col4, colf, best, bl); }
    else             { conv_tile< 85>(col4, colf, best, bl);
                       conv_tile<100>(col4, colf, best, bl); }
    __syncthreads();                       // conv done: X now dead

    // ---- Phase F: cross-wave argmax via aux ----
    Xa[s * 64 + f] = best;
    reinterpret_cast<int*>(Xa)[256 + s * 64 + f] = bl;
    __syncthreads();

    if (s == 0) {
        float bv = Xa[f];
        int   L  = reinterpret_cast<int*>(Xa)[256 + f];
        #pragma unroll
        for (int c = 1; c < 4; ++c) {
            const float vv = Xa[c * 64 + f];
            const int   lv = reinterpret_cast<int*>(Xa)[256 + c * 64 + f];
            if (vv > bv || (vv == bv && lv < L)) { bv = vv; L = lv; }
        }
        const float pitch = SR_F / (float)L;
        out[(size_t)b * TFRAMES + t0 + f] = (mx < 1e-8f) ? 0.0f : pitch;
    }
}

extern "C" void kernel_launch(void* const* d_in, const int* in_sizes, int n_in,
                              void* d_out, int out_size, void* d_ws, size_t ws_size,
                              hipStream_t stream) {
    const float* audio = (const float*)d_in[0];
    float* out = (float*)d_out;
    pitch_kernel<<<dim3(1024), dim3(256), 0, stream>>>(audio, out);
}